// Round 12
// baseline (101.656 us; speedup 1.0000x reference)
//
#include <hip/hip_runtime.h>
#include <hip/hip_bf16.h>

typedef __attribute__((ext_vector_type(8))) short bf16x8;
typedef __attribute__((ext_vector_type(4))) float f32x4;

#define Bb 64
#define Ss 100
#define Ff 128
#define Hh 8
#define ROWS (Bb * Ss)              // 6400
#define ELEMS (ROWS * Ff)           // 819200

// fp32 -> bf16 round-to-nearest-even
__device__ __forceinline__ unsigned short f2bf(float f) {
    unsigned u = __float_as_uint(f);
    u += 0x7FFFu + ((u >> 16) & 1u);
    return (unsigned short)(u >> 16);
}

// load 8 consecutive fp32 -> bf16x8 A-fragment
__device__ __forceinline__ bf16x8 load_a8(const float* p) {
    float4 x0 = *(const float4*)p;
    float4 x1 = *(const float4*)(p + 4);
    bf16x8 a;
    a[0] = (short)f2bf(x0.x); a[1] = (short)f2bf(x0.y);
    a[2] = (short)f2bf(x0.z); a[3] = (short)f2bf(x0.w);
    a[4] = (short)f2bf(x1.x); a[5] = (short)f2bf(x1.y);
    a[6] = (short)f2bf(x1.z); a[7] = (short)f2bf(x1.w);
    return a;
}

// ---------------------------------------------------------------------------
// Fused QKV projection + attention. Blocks 0..511 = (b,h); blocks 512..519
// convert Wo -> WtO (bf16 transposed) for the output projection.
// 448 threads = 7 waves; wave w owns query rows 16w..16w+15 (S padded to 112).
//
// LDS map (unsigned short indices):
//   Wsl  @     0 : 3 x [16][136]  W head-slices, W^T layout (n, k)
//   Qs   @  6528 : [112][40]      Q rows (d 0..15 data, 16..39 zero)
//   Ks   @ 11008 : [112][40]
//   Vt   @ 15488 : [16][136]      V transposed (d, s)
//   Ps   @ 17664 : 7 x [16][136]  wave-private P
//   total 32896 shorts = 65792 B  -> 2 blocks/CU
// ---------------------------------------------------------------------------
__global__ __launch_bounds__(448) void fused_qkv_attn_kernel(
    const float* __restrict__ q, const float* __restrict__ k, const float* __restrict__ v,
    const float* __restrict__ Wq, const float* __restrict__ bq,
    const float* __restrict__ Wk, const float* __restrict__ bk,
    const float* __restrict__ Wv, const float* __restrict__ bv,
    const float* __restrict__ Wo,
    unsigned short* __restrict__ ao, unsigned short* __restrict__ WtO)
{
    const int blk = blockIdx.x;
    const int t = threadIdx.x;

    if (blk >= Bb * Hh) {                     // tail: convert Wo (8 blocks)
        if (t < 256) {
            const int kb = blk - Bb * Hh;     // 0..7
            const int n  = t >> 1;
            const int k0 = kb * 16 + (t & 1) * 8;
            bf16x8 vv;
#pragma unroll
            for (int j = 0; j < 8; ++j) vv[j] = (short)f2bf(Wo[(k0 + j) * Ff + n]);
            *(bf16x8*)&WtO[n * Ff + k0] = vv;
        }
        return;
    }

    __shared__ unsigned short lds[32896];
    const int b = blk >> 3, h = blk & 7;

    // zero Qs/Ks/Vt/Ps: shorts 6528..32895 = 26368 shorts = 3296 int4
    {
        int4* z = (int4*)&lds[6528];
        for (int i = t; i < 3296; i += 448) z[i] = make_int4(0, 0, 0, 0);
    }
    // stage W head-slices: Wsl[p][n][136] = Wp[k][h*16+n], bf16
    for (int i = t; i < 3 * 2048; i += 448) {
        const int p = i >> 11, rem = i & 2047;
        const int kk = rem >> 4, n = rem & 15;
        const float* Wp = p == 0 ? Wq : p == 1 ? Wk : Wv;
        lds[p * 2176 + n * 136 + kk] = f2bf(Wp[kk * Ff + h * 16 + n]);
    }
    __syncthreads();

    const int w = t >> 6, lane = t & 63, m = lane & 15, g = lane >> 4;
    f32x4 zz = {0.f, 0.f, 0.f, 0.f};

    // ---- projection: rows 16w..16w+15 of Q/K/V for this (b,h) ----
    const int rowb = w * 16 + m;
    const int rowc = rowb < Ss ? rowb : Ss - 1;          // clamp pad rows
    const float* xq = q + (b * Ss + rowc) * Ff + g * 8;
    const float* xk = k + (b * Ss + rowc) * Ff + g * 8;
    const float* xv = v + (b * Ss + rowc) * Ff + g * 8;

    f32x4 accq = zz, acck = zz, accv = zz;
#pragma unroll
    for (int kk = 0; kk < 4; ++kk) {
        const int xo = kk * 32;
        const int wo = m * 136 + kk * 32 + g * 8;
        bf16x8 bqf = *(const bf16x8*)&lds[wo];
        bf16x8 bkf = *(const bf16x8*)&lds[2176 + wo];
        bf16x8 bvf = *(const bf16x8*)&lds[4352 + wo];
        accq = __builtin_amdgcn_mfma_f32_16x16x32_bf16(load_a8(xq + xo), bqf, accq, 0, 0, 0);
        acck = __builtin_amdgcn_mfma_f32_16x16x32_bf16(load_a8(xk + xo), bkf, acck, 0, 0, 0);
        accv = __builtin_amdgcn_mfma_f32_16x16x32_bf16(load_a8(xv + xo), bvf, accv, 0, 0, 0);
    }
    // epilogue: C row = w*16 + g*4 + r, col d = m
    {
        const float bbq = bq[h * 16 + m];
        const float bbk = bk[h * 16 + m];
        const float bbv = bv[h * 16 + m];
#pragma unroll
        for (int r = 0; r < 4; ++r) {
            const int row = w * 16 + g * 4 + r;          // 0..111
            lds[6528  + row * 40 + m]  = f2bf(accq[r] + bbq);
            lds[11008 + row * 40 + m]  = f2bf(acck[r] + bbk);
            lds[15488 + m * 136 + row] = f2bf(accv[r] + bbv);
        }
    }
    __syncthreads();

    // ---- QK^T: scores [16][112], K-dim = 32 (d 16..31 zero) ----
    bf16x8 aq = *(const bf16x8*)&lds[6528 + (w * 16 + m) * 40 + g * 8];
    f32x4 sc[7];
#pragma unroll
    for (int tt = 0; tt < 7; ++tt) {
        bf16x8 bkf = *(const bf16x8*)&lds[11008 + (tt * 16 + m) * 40 + g * 8];
        sc[tt] = __builtin_amdgcn_mfma_f32_16x16x32_bf16(aq, bkf, zz, 0, 0, 0);
    }

    // ---- masked softmax (rows rbase..rbase+3, col = tt*16+m) ----
    const int rbase = w * 16 + g * 4;
    float mx[4], sum[4], invl[4];
#pragma unroll
    for (int r = 0; r < 4; ++r) mx[r] = -3.0e38f;
#pragma unroll
    for (int tt = 0; tt < 7; ++tt)
#pragma unroll
        for (int r = 0; r < 4; ++r) {
            float sv = (tt * 16 + m <= rbase + r) ? sc[tt][r] * 0.25f : -1.0e30f;
            sc[tt][r] = sv;
            mx[r] = fmaxf(mx[r], sv);
        }
#pragma unroll
    for (int off = 1; off < 16; off <<= 1)
#pragma unroll
        for (int r = 0; r < 4; ++r) mx[r] = fmaxf(mx[r], __shfl_xor(mx[r], off));
#pragma unroll
    for (int r = 0; r < 4; ++r) sum[r] = 0.f;

    unsigned short* Pw = &lds[17664 + w * 2176];         // wave-private [16][136]
#pragma unroll
    for (int tt = 0; tt < 7; ++tt)
#pragma unroll
        for (int r = 0; r < 4; ++r) {
            float e = __expf(sc[tt][r] - mx[r]);
            sum[r] += e;
            Pw[(g * 4 + r) * 136 + tt * 16 + m] = f2bf(e);
        }
#pragma unroll
    for (int off = 1; off < 16; off <<= 1)
#pragma unroll
        for (int r = 0; r < 4; ++r) sum[r] += __shfl_xor(sum[r], off);
#pragma unroll
    for (int r = 0; r < 4; ++r) invl[r] = 1.0f / sum[r];

    // ---- PV: O[16][16] = P[16][128] * V[128][16] ----
    f32x4 oacc = zz;
#pragma unroll
    for (int kk = 0; kk < 128; kk += 32) {
        bf16x8 ap = *(const bf16x8*)&Pw[m * 136 + kk + g * 8];
        bf16x8 bvf = *(const bf16x8*)&lds[15488 + m * 136 + kk + g * 8];
        oacc = __builtin_amdgcn_mfma_f32_16x16x32_bf16(ap, bvf, oacc, 0, 0, 0);
    }
#pragma unroll
    for (int r = 0; r < 4; ++r) {
        const int s = rbase + r;
        if (s < Ss)
            ao[(b * Ss + s) * Ff + h * 16 + m] = f2bf(oacc[r] * invl[r]);
    }
}

// ---------------------------------------------------------------------------
// Output projection: 64 rows x 128 cols per block, bf16 in, fp32 out. grid 100.
// ---------------------------------------------------------------------------
__global__ __launch_bounds__(256) void proj_out_kernel(
    const unsigned short* __restrict__ ao, const unsigned short* __restrict__ WtO,
    const float* __restrict__ bo, float* __restrict__ out)
{
    __shared__ unsigned short Xs[64 * 136];
    __shared__ unsigned short Ws[128 * 136];
    const int t = threadIdx.x;
    const int r0 = blockIdx.x * 64;
#pragma unroll
    for (int i = 0; i < 4; ++i) {
        int idx = t + i * 256;                 // 0..1023
        int r = idx >> 4, c8 = (idx & 15) * 8;
        *(bf16x8*)&Xs[r * 136 + c8] = *(const bf16x8*)&ao[(r0 + r) * Ff + c8];
    }
#pragma unroll
    for (int i = 0; i < 8; ++i) {
        int r = (t >> 4) + i * 16, c8 = (t & 15) * 8;
        *(bf16x8*)&Ws[r * 136 + c8] = *(const bf16x8*)&WtO[r * Ff + c8];
    }
    __syncthreads();

    const int w = t >> 6, lane = t & 63, m = lane & 15, g = lane >> 4;
    f32x4 zz = {0.f, 0.f, 0.f, 0.f};
    f32x4 acc[8];
#pragma unroll
    for (int n = 0; n < 8; ++n) acc[n] = zz;
#pragma unroll
    for (int kk = 0; kk < 128; kk += 32) {
        bf16x8 a = *(const bf16x8*)&Xs[(w * 16 + m) * 136 + kk + g * 8];
#pragma unroll
        for (int n = 0; n < 8; ++n) {
            bf16x8 bf = *(const bf16x8*)&Ws[(n * 16 + m) * 136 + kk + g * 8];
            acc[n] = __builtin_amdgcn_mfma_f32_16x16x32_bf16(a, bf, acc[n], 0, 0, 0);
        }
    }

#pragma unroll
    for (int n = 0; n < 8; ++n) {
        float bb = bo[n * 16 + m];
#pragma unroll
        for (int r = 0; r < 4; ++r) {
            int row = r0 + w * 16 + g * 4 + r;
            out[row * Ff + n * 16 + m] = acc[n][r] + bb;
        }
    }
}

// ---------------------------------------------------------------------------
extern "C" void kernel_launch(void* const* d_in, const int* in_sizes, int n_in,
                              void* d_out, int out_size, void* d_ws, size_t ws_size,
                              hipStream_t stream) {
    const float* q  = (const float*)d_in[0];
    const float* k  = (const float*)d_in[1];
    const float* v  = (const float*)d_in[2];
    // d_in[3] = causal mask (applied analytically)
    const float* Wq = (const float*)d_in[4];
    const float* bq = (const float*)d_in[5];
    const float* Wk = (const float*)d_in[6];
    const float* bk = (const float*)d_in[7];
    const float* Wv = (const float*)d_in[8];
    const float* bv = (const float*)d_in[9];
    const float* Wo = (const float*)d_in[10];
    const float* bo = (const float*)d_in[11];

    float* out = (float*)d_out;
    unsigned short* wsu = (unsigned short*)d_ws;
    unsigned short* WtO = wsu;                       // [128][128] bf16 (W_o^T)
    unsigned short* ao  = wsu + 16384;               // [6400][128] bf16

    fused_qkv_attn_kernel<<<dim3(Bb * Hh + 8), dim3(448), 0, stream>>>(
        q, k, v, Wq, bq, Wk, bk, Wv, bv, Wo, ao, WtO);
    proj_out_kernel<<<dim3(100), dim3(256), 0, stream>>>(ao, WtO, bo, out);
}

// Round 14
// 98.776 us; speedup vs baseline: 1.0292x; 1.0292x over previous
//
#include <hip/hip_runtime.h>
#include <hip/hip_bf16.h>

typedef __attribute__((ext_vector_type(8))) short bf16x8;
typedef __attribute__((ext_vector_type(4))) float f32x4;
typedef __attribute__((ext_vector_type(4))) unsigned short us4;

#define Bb 64
#define Ss 100
#define Ff 128
#define Hh 8

// fp32 -> bf16 round-to-nearest-even
__device__ __forceinline__ unsigned short f2bf(float f) {
    unsigned u = __float_as_uint(f);
    u += 0x7FFFu + ((u >> 16) & 1u);
    return (unsigned short)(u >> 16);
}

// load 8 consecutive fp32 -> bf16x8 A-fragment
__device__ __forceinline__ bf16x8 load_a8(const float* p) {
    float4 x0 = *(const float4*)p;
    float4 x1 = *(const float4*)(p + 4);
    bf16x8 a;
    a[0] = (short)f2bf(x0.x); a[1] = (short)f2bf(x0.y);
    a[2] = (short)f2bf(x0.z); a[3] = (short)f2bf(x0.w);
    a[4] = (short)f2bf(x1.x); a[5] = (short)f2bf(x1.y);
    a[6] = (short)f2bf(x1.z); a[7] = (short)f2bf(x1.w);
    return a;
}

// ---------------------------------------------------------------------------
// Fused QKV projection + attention. Blocks 0..511 = (b,h); blocks 512..519
// convert Wo -> WtO. 448 threads = 7 waves; wave w owns query rows 16w..16w+15.
//
// LDS map (unsigned short indices), 17664 shorts = 35328 B:
//   Wsl @     0 : 3 x [16][136]  W head-slices (n,k)   -- dead after proj
//   Qs  @  6528 : [112][40]                            -- dead after QK^T
//   Ks  @ 11008 : [112][40]                            -- dead after QK^T
//   Vt  @ 15488 : [16][136]  V transposed (d,s)
//   Ps  @     0 : 7 x [16][136]  ALIASES Wsl/Qs/Ks (after barrier #3)
// ---------------------------------------------------------------------------
__global__ __launch_bounds__(448, 6) void fused_qkv_attn_kernel(
    const float* __restrict__ q, const float* __restrict__ k, const float* __restrict__ v,
    const float* __restrict__ Wq, const float* __restrict__ bq,
    const float* __restrict__ Wk, const float* __restrict__ bk,
    const float* __restrict__ Wv, const float* __restrict__ bv,
    const float* __restrict__ Wo,
    unsigned short* __restrict__ ao, unsigned short* __restrict__ WtO)
{
    const int blk = blockIdx.x;
    const int t = threadIdx.x;

    if (blk >= Bb * Hh) {                     // tail: convert Wo (8 blocks)
        if (t < 256) {
            const int kb = blk - Bb * Hh;     // 0..7
            const int n  = t >> 1;
            const int k0 = kb * 16 + (t & 1) * 8;
            bf16x8 vv;
#pragma unroll
            for (int j = 0; j < 8; ++j) vv[j] = (short)f2bf(Wo[(k0 + j) * Ff + n]);
            *(bf16x8*)&WtO[n * Ff + k0] = vv;
        }
        return;
    }

    __shared__ unsigned short lds[17664];
    const int b = blk >> 3, h = blk & 7;

    // ---- stage W head-slices via float4: Wsl[p][n][136] = Wp[k][h*16+n] ----
    for (int i = t; i < 1536; i += 448) {
        const int p = i >> 9, rem = i & 511;
        const int kk = rem >> 2, n4 = (rem & 3) * 4;
        const float* Wp = p == 0 ? Wq : p == 1 ? Wk : Wv;
        const float4 wv = *(const float4*)&Wp[kk * Ff + h * 16 + n4];
        lds[p * 2176 + (n4 + 0) * 136 + kk] = f2bf(wv.x);
        lds[p * 2176 + (n4 + 1) * 136 + kk] = f2bf(wv.y);
        lds[p * 2176 + (n4 + 2) * 136 + kk] = f2bf(wv.z);
        lds[p * 2176 + (n4 + 3) * 136 + kk] = f2bf(wv.w);
    }
    // ---- zero only the read pad bands: Qs/Ks cols 16..31, Vt cols 100..127 ----
    {
        const us4 z4 = {0, 0, 0, 0};
        for (int i = t; i < 1008; i += 448) {
            if (i < 896) {
                const int row = i >> 3, rem = i & 7;
                const int base = (rem >> 2) ? 11008 : 6528;
                *(us4*)&lds[base + row * 40 + 16 + (rem & 3) * 4] = z4;
            } else {
                const int j = i - 896;                   // 0..111
                *(us4*)&lds[15488 + (j / 7) * 136 + 100 + (j % 7) * 4] = z4;
            }
        }
    }
    __syncthreads();

    const int w = t >> 6, lane = t & 63, m = lane & 15, g = lane >> 4;
    f32x4 zz = {0.f, 0.f, 0.f, 0.f};

    // ---- projection: rows 16w..16w+15 of Q/K/V for this (b,h) ----
    const int rowb = w * 16 + m;
    const int rowc = rowb < Ss ? rowb : Ss - 1;          // clamp pad rows
    const float* xq = q + (b * Ss + rowc) * Ff + g * 8;
    const float* xk = k + (b * Ss + rowc) * Ff + g * 8;
    const float* xv = v + (b * Ss + rowc) * Ff + g * 8;

    f32x4 accq = zz, acck = zz, accv = zz;
#pragma unroll
    for (int kk = 0; kk < 4; ++kk) {
        const int xo = kk * 32;
        const int wo = m * 136 + kk * 32 + g * 8;
        bf16x8 bqf = *(const bf16x8*)&lds[wo];
        bf16x8 bkf = *(const bf16x8*)&lds[2176 + wo];
        bf16x8 bvf = *(const bf16x8*)&lds[4352 + wo];
        accq = __builtin_amdgcn_mfma_f32_16x16x32_bf16(load_a8(xq + xo), bqf, accq, 0, 0, 0);
        acck = __builtin_amdgcn_mfma_f32_16x16x32_bf16(load_a8(xk + xo), bkf, acck, 0, 0, 0);
        accv = __builtin_amdgcn_mfma_f32_16x16x32_bf16(load_a8(xv + xo), bvf, accv, 0, 0, 0);
    }
    // epilogue: C row = w*16 + g*4 + r, col d = m
    {
        const float bbq = bq[h * 16 + m];
        const float bbk = bk[h * 16 + m];
        const float bbv = bv[h * 16 + m];
#pragma unroll
        for (int r = 0; r < 4; ++r) {
            const int row = w * 16 + g * 4 + r;          // 0..111
            lds[6528  + row * 40 + m]  = f2bf(accq[r] + bbq);
            lds[11008 + row * 40 + m]  = f2bf(acck[r] + bbk);
            lds[15488 + m * 136 + row] = f2bf(accv[r] + bbv);
        }
    }
    __syncthreads();

    // ---- QK^T: scores [16][112], K-dim = 32 (d 16..31 zero) ----
    bf16x8 aq = *(const bf16x8*)&lds[6528 + (w * 16 + m) * 40 + g * 8];
    f32x4 sc[7];
#pragma unroll
    for (int tt = 0; tt < 7; ++tt) {
        bf16x8 bkf = *(const bf16x8*)&lds[11008 + (tt * 16 + m) * 40 + g * 8];
        sc[tt] = __builtin_amdgcn_mfma_f32_16x16x32_bf16(aq, bkf, zz, 0, 0, 0);
    }

    // ---- mask + row max (registers only, overlaps barrier wait) ----
    const int rbase = w * 16 + g * 4;
    float mx[4], sum[4], invl[4];
#pragma unroll
    for (int r = 0; r < 4; ++r) mx[r] = -3.0e38f;
#pragma unroll
    for (int tt = 0; tt < 7; ++tt)
#pragma unroll
        for (int r = 0; r < 4; ++r) {
            float sv = (tt * 16 + m <= rbase + r) ? sc[tt][r] * 0.25f : -1.0e30f;
            sc[tt][r] = sv;
            mx[r] = fmaxf(mx[r], sv);
        }
#pragma unroll
    for (int off = 1; off < 16; off <<= 1)
#pragma unroll
        for (int r = 0; r < 4; ++r) mx[r] = fmaxf(mx[r], __shfl_xor(mx[r], off));

    __syncthreads();                       // Qs/Ks/Wsl now dead -> Ps aliases them

    unsigned short* Pw = &lds[w * 2176];   // wave-private [16][136]
    {   // zero P pad cols 112..127 (stale W/Q/K data underneath)
        const us4 z4 = {0, 0, 0, 0};
        *(us4*)&Pw[m * 136 + 112 + g * 4] = z4;
    }
#pragma unroll
    for (int r = 0; r < 4; ++r) sum[r] = 0.f;
#pragma unroll
    for (int tt = 0; tt < 7; ++tt)
#pragma unroll
        for (int r = 0; r < 4; ++r) {
            float e = __expf(sc[tt][r] - mx[r]);
            sum[r] += e;
            Pw[(g * 4 + r) * 136 + tt * 16 + m] = f2bf(e);
        }
#pragma unroll
    for (int off = 1; off < 16; off <<= 1)
#pragma unroll
        for (int r = 0; r < 4; ++r) sum[r] += __shfl_xor(sum[r], off);
#pragma unroll
    for (int r = 0; r < 4; ++r) invl[r] = 1.0f / sum[r];

    // ---- PV: O[16][16] = P[16][128] * V[128][16] ----
    f32x4 oacc = zz;
#pragma unroll
    for (int kk = 0; kk < 128; kk += 32) {
        bf16x8 ap  = *(const bf16x8*)&Pw[m * 136 + kk + g * 8];
        bf16x8 bvf = *(const bf16x8*)&lds[15488 + m * 136 + kk + g * 8];
        oacc = __builtin_amdgcn_mfma_f32_16x16x32_bf16(ap, bvf, oacc, 0, 0, 0);
    }
#pragma unroll
    for (int r = 0; r < 4; ++r) {
        const int s = rbase + r;
        if (s < Ss)
            ao[(b * Ss + s) * Ff + h * 16 + m] = f2bf(oacc[r] * invl[r]);
    }
}

// ---------------------------------------------------------------------------
// Output projection: 64 rows x 128 cols per block, bf16 in, fp32 out. grid 100.
// ---------------------------------------------------------------------------
__global__ __launch_bounds__(256) void proj_out_kernel(
    const unsigned short* __restrict__ ao, const unsigned short* __restrict__ WtO,
    const float* __restrict__ bo, float* __restrict__ out)
{
    __shared__ unsigned short Xs[64 * 136];
    __shared__ unsigned short Ws[128 * 136];
    const int t = threadIdx.x;
    const int r0 = blockIdx.x * 64;
#pragma unroll
    for (int i = 0; i < 4; ++i) {
        int idx = t + i * 256;                 // 0..1023
        int r = idx >> 4, c8 = (idx & 15) * 8;
        *(bf16x8*)&Xs[r * 136 + c8] = *(const bf16x8*)&ao[(r0 + r) * Ff + c8];
    }
#pragma unroll
    for (int i = 0; i < 8; ++i) {
        int r = (t >> 4) + i * 16, c8 = (t & 15) * 8;
        *(bf16x8*)&Ws[r * 136 + c8] = *(const bf16x8*)&WtO[r * Ff + c8];
    }
    __syncthreads();

    const int w = t >> 6, lane = t & 63, m = lane & 15, g = lane >> 4;
    f32x4 zz = {0.f, 0.f, 0.f, 0.f};
    f32x4 acc[8];
#pragma unroll
    for (int n = 0; n < 8; ++n) acc[n] = zz;
#pragma unroll
    for (int kk = 0; kk < 128; kk += 32) {
        bf16x8 a = *(const bf16x8*)&Xs[(w * 16 + m) * 136 + kk + g * 8];
#pragma unroll
        for (int n = 0; n < 8; ++n) {
            bf16x8 bf = *(const bf16x8*)&Ws[(n * 16 + m) * 136 + kk + g * 8];
            acc[n] = __builtin_amdgcn_mfma_f32_16x16x32_bf16(a, bf, acc[n], 0, 0, 0);
        }
    }

#pragma unroll
    for (int n = 0; n < 8; ++n) {
        float bb = bo[n * 16 + m];
#pragma unroll
        for (int r = 0; r < 4; ++r) {
            int row = r0 + w * 16 + g * 4 + r;
            out[row * Ff + n * 16 + m] = acc[n][r] + bb;
        }
    }
}

// ---------------------------------------------------------------------------
extern "C" void kernel_launch(void* const* d_in, const int* in_sizes, int n_in,
                              void* d_out, int out_size, void* d_ws, size_t ws_size,
                              hipStream_t stream) {
    const float* q  = (const float*)d_in[0];
    const float* k  = (const float*)d_in[1];
    const float* v  = (const float*)d_in[2];
    // d_in[3] = causal mask (applied analytically)
    const float* Wq = (const float*)d_in[4];
    const float* bq = (const float*)d_in[5];
    const float* Wk = (const float*)d_in[6];
    const float* bk = (const float*)d_in[7];
    const float* Wv = (const float*)d_in[8];
    const float* bv = (const float*)d_in[9];
    const float* Wo = (const float*)d_in[10];
    const float* bo = (const float*)d_in[11];

    float* out = (float*)d_out;
    unsigned short* wsu = (unsigned short*)d_ws;
    unsigned short* WtO = wsu;                       // [128][128] bf16 (W_o^T)
    unsigned short* ao  = wsu + 16384;               // [6400][128] bf16

    fused_qkv_attn_kernel<<<dim3(Bb * Hh + 8), dim3(448), 0, stream>>>(
        q, k, v, Wq, bq, Wk, bk, Wv, bv, Wo, ao, WtO);
    proj_out_kernel<<<dim3(100), dim3(256), 0, stream>>>(ao, WtO, bo, out);
}